// Round 13
// baseline (43.667 us; speedup 1.0000x reference)
//
#include <hip/hip_runtime.h>

// DecoderLayer: out[k,n,m] = tanh(sum_p w[k,p]*prev[idx[k,p],n,m] + b[k]),
// gated by (#active parents >= 12).  M=2048, K=4096, NN=4096 (64x64), P=16.
//
// R13: keep R11/R12's proven gather geometry (lane-QUAD per node, many
// row-start phases -> ~14cyc/instr) but halve the tile so TWO 1024-thread
// blocks fit per CU (32 waves = full thread occupancy; R12 measured 50% of
// cycles with both pipes idle at 4 waves/SIMD).
//   POS_TILE=16, rows = 32B bf16 + 8B pad = 40B (16 start phases),
//   chunk = ds_read_b64 (4 positions, 8B-aligned). LDS = 80KiB/block.
//   Each tile slice staged exactly once (33.5MB total, was 64MB).

#define M_ROWS   2048
#define K_NODES  4096
#define NN       4096
#define POS_TILE 16
#define NTHREADS 1024
#define ROW_B    40                          // bytes per padded bf16 row
#define LDS_BYTES (M_ROWS * ROW_B)           // 81920 = 80 KiB -> 2 blocks/CU
#define OUT_ELEMS (K_NODES * NN)
#define ACTIVE_THRESHOLD 12

typedef float f32x4 __attribute__((ext_vector_type(4)));
typedef unsigned short u16x4 __attribute__((ext_vector_type(4)));

__device__ __forceinline__ float fast_tanh(float x) {
  float ax = __builtin_fabsf(x);
  float e  = __expf(-2.0f * ax);
  float r  = (1.0f - e) * __builtin_amdgcn_rcpf(1.0f + e);
  return __builtin_copysignf(r, x);
}

__device__ __forceinline__ unsigned short f2bf_rne(float f) {
  unsigned u = __float_as_uint(f);
  u += 0x7FFFu + ((u >> 16) & 1u);           // round-to-nearest-even
  return (unsigned short)(u >> 16);
}

// Gate precompute (off hot path). Runtime-detects isact marshaling:
// any 32-bit word >1 in the first 2048 bytes implies packed bytes.
__global__ __launch_bounds__(256) void act_kernel(
    const int* __restrict__ pidx, const unsigned int* __restrict__ isact,
    float* __restrict__ outact) {
  __shared__ int mode_sh;
  if (threadIdx.x == 0) mode_sh = 0;
  __syncthreads();
  int bad = 0;
  for (int i = threadIdx.x; i < 512; i += 256) bad |= (isact[i] > 1u);
  if (bad) atomicOr(&mode_sh, 1);
  __syncthreads();
  const int shift = mode_sh ? 0 : 2;   // LSB byte of a 0/1 int32 == its value
  const unsigned char* actb = (const unsigned char*)isact;

  int k = blockIdx.x * 256 + threadIdx.x;
  const int4* ip = (const int4*)(pidx + k * 16);
  int4 ia = ip[0], ib = ip[1], ic = ip[2], id4 = ip[3];
  int ids[16] = {ia.x, ia.y, ia.z, ia.w, ib.x, ib.y, ib.z, ib.w,
                 ic.x, ic.y, ic.z, ic.w, id4.x, id4.y, id4.z, id4.w};
  int n = 0;
  #pragma unroll
  for (int p = 0; p < 16; ++p) n += (actb[ids[p] << shift] != 0);
  outact[k] = (n >= ACTIVE_THRESHOLD) ? 1.0f : 0.0f;
}

// unpack-and-FMA one parent chunk: 4 bf16 positions into 4 scalar f32 accs
#define PFMA4(vv, wv)                                             \
  { float wv_ = (wv);                                             \
    a0 += wv_ * __uint_as_float((unsigned)(vv)[0] << 16);         \
    a1 += wv_ * __uint_as_float((unsigned)(vv)[1] << 16);         \
    a2 += wv_ * __uint_as_float((unsigned)(vv)[2] << 16);         \
    a3 += wv_ * __uint_as_float((unsigned)(vv)[3] << 16); }

__global__ __launch_bounds__(NTHREADS, 8) void decoder_kernel(
    const float* __restrict__ prev, const int* __restrict__ pidx,
    const float* __restrict__ w, const float* __restrict__ b,
    const float* __restrict__ actf, float* __restrict__ out,
    float* __restrict__ outact) {
  extern __shared__ char xb[];               // [2048 rows][40 B] bf16 tile
  const int tid  = threadIdx.x;
  const int bid  = blockIdx.x;               // 0..255 (= tile)
  const int pos0 = bid * POS_TILE;

  // ---- stage prev[:, pos0:pos0+16] as bf16-RNE into 40B padded rows ----
  // 8B chunks: thread handles (row r, chunk c): read 4 f32, write u16x4.
  #pragma unroll
  for (int it = 0; it < 8; ++it) {
    int ci = (it << 10) + tid;               // 0..8191
    int r = ci >> 2, c = ci & 3;
    f32x4 v = *(const f32x4*)(prev + r * NN + pos0 + (c << 2));
    u16x4 o;
    o[0] = f2bf_rne(v.x); o[1] = f2bf_rne(v.y);
    o[2] = f2bf_rne(v.z); o[3] = f2bf_rne(v.w);
    *(u16x4*)(xb + r * ROW_B + (c << 3)) = o;   // ds_write_b64, 8B aligned
  }
  __syncthreads();

  const int q  = tid & 3;                    // chunk (4 positions) this lane owns
  const int s  = tid >> 2;                   // node slot 0..255
  const int qb = q << 3;                     // byte offset within row

  for (int it = 0; it < 16; ++it) {
    int n = (it << 8) + s;
    const int4*   ip = (const int4*)(pidx + (n << 4));
    const float4* wp = (const float4*)(w + (n << 4));
    float bk = b[n];
    float g  = actf[n];                      // 0.0 / 1.0

    float a0 = bk, a1 = bk, a2 = bk, a3 = bk;

    #pragma unroll
    for (int bb = 0; bb < 4; ++bb) {         // 4 batches of 4 parents
      int4   iv = ip[bb];
      float4 wv = wp[bb];
      // 4 independent ds_read_b64 (quad covers the row's 32B)
      u16x4 v0 = *(const u16x4*)(xb + iv.x * ROW_B + qb);
      u16x4 v1 = *(const u16x4*)(xb + iv.y * ROW_B + qb);
      u16x4 v2 = *(const u16x4*)(xb + iv.z * ROW_B + qb);
      u16x4 v3 = *(const u16x4*)(xb + iv.w * ROW_B + qb);
      __builtin_amdgcn_sched_barrier(0);     // keep 4 reads in flight
      PFMA4(v0, wv.x) PFMA4(v1, wv.y) PFMA4(v2, wv.z) PFMA4(v3, wv.w)
    }

    f32x4 o;
    o.x = fast_tanh(a0) * g;
    o.y = fast_tanh(a1) * g;
    o.z = fast_tanh(a2) * g;
    o.w = fast_tanh(a3) * g;
    // quad writes node n's full 64B line
    *(f32x4*)(out + ((size_t)n << 12) + pos0 + (q << 2)) = o;

    if (bid == 0 && q == 0) outact[n] = g;   // block 0 covers all nodes
  }
}

extern "C" void kernel_launch(void* const* d_in, const int* in_sizes, int n_in,
                              void* d_out, int out_size, void* d_ws, size_t ws_size,
                              hipStream_t stream) {
  const float* prev  = (const float*)d_in[0];
  const void*  isact = d_in[1];
  const int*   pidx  = (const int*)d_in[2];
  const float* w     = (const float*)d_in[3];
  const float* b     = (const float*)d_in[4];
  float* out    = (float*)d_out;
  float* outact = out + OUT_ELEMS;

  (void)hipFuncSetAttribute((const void*)decoder_kernel,
                            hipFuncAttributeMaxDynamicSharedMemorySize, LDS_BYTES);

  act_kernel<<<K_NODES / 256, 256, 0, stream>>>(
      pidx, (const unsigned int*)isact, outact);
  decoder_kernel<<<NN / POS_TILE, NTHREADS, LDS_BYTES, stream>>>(
      prev, pidx, w, b, outact, out, outact);
}

// Round 14
// 41.146 us; speedup vs baseline: 1.0613x; 1.0613x over previous
//
#include <hip/hip_runtime.h>

// DecoderLayer: out[k,n,m] = tanh(sum_p w[k,p]*prev[idx[k,p],n,m] + b[k]),
// gated by (#active parents >= 12).  M=2048, K=4096, NN=4096 (64x64), P=16.
//
// R14: law v3 (R4/R6/R11/R12/R13): random-row LDS gather ~15cyc/instr
// REGARDLESS of width -> minimize instruction count. R12 had 4096 gather
// instrs/block (64B rows, quad); here: POS_TILE=16, rows = 32B bf16 data
// + 16B pad = 48B (16B-aligned for b128, 8 start phases), lane-PAIR per
// node -> 2048 instrs/block. Per-lane VALU identical to R12 (8 pos/lane).
// LDS 96KiB, 1024 threads, 1 block/CU, grid = 256 tiles.

#define M_ROWS   2048
#define K_NODES  4096
#define NN       4096
#define POS_TILE 16
#define NTHREADS 1024
#define ROW_B    48                          // bytes per padded bf16 row
#define LDS_BYTES (M_ROWS * ROW_B)           // 98304 = 96 KiB
#define OUT_ELEMS (K_NODES * NN)
#define ACTIVE_THRESHOLD 12

typedef float f32x4 __attribute__((ext_vector_type(4)));
typedef unsigned short u16x8 __attribute__((ext_vector_type(8)));

__device__ __forceinline__ float fast_tanh(float x) {
  float ax = __builtin_fabsf(x);
  float e  = __expf(-2.0f * ax);
  float r  = (1.0f - e) * __builtin_amdgcn_rcpf(1.0f + e);
  return __builtin_copysignf(r, x);
}

__device__ __forceinline__ unsigned short f2bf_rne(float f) {
  unsigned u = __float_as_uint(f);
  u += 0x7FFFu + ((u >> 16) & 1u);           // round-to-nearest-even
  return (unsigned short)(u >> 16);
}

// Gate precompute (off hot path). Runtime-detects isact marshaling:
// any 32-bit word >1 in the first 2048 bytes implies packed bytes.
__global__ __launch_bounds__(256) void act_kernel(
    const int* __restrict__ pidx, const unsigned int* __restrict__ isact,
    float* __restrict__ outact) {
  __shared__ int mode_sh;
  if (threadIdx.x == 0) mode_sh = 0;
  __syncthreads();
  int bad = 0;
  for (int i = threadIdx.x; i < 512; i += 256) bad |= (isact[i] > 1u);
  if (bad) atomicOr(&mode_sh, 1);
  __syncthreads();
  const int shift = mode_sh ? 0 : 2;   // LSB byte of a 0/1 int32 == its value
  const unsigned char* actb = (const unsigned char*)isact;

  int k = blockIdx.x * 256 + threadIdx.x;
  const int4* ip = (const int4*)(pidx + k * 16);
  int4 ia = ip[0], ib = ip[1], ic = ip[2], id4 = ip[3];
  int ids[16] = {ia.x, ia.y, ia.z, ia.w, ib.x, ib.y, ib.z, ib.w,
                 ic.x, ic.y, ic.z, ic.w, id4.x, id4.y, id4.z, id4.w};
  int n = 0;
  #pragma unroll
  for (int p = 0; p < 16; ++p) n += (actb[ids[p] << shift] != 0);
  outact[k] = (n >= ACTIVE_THRESHOLD) ? 1.0f : 0.0f;
}

// unpack-and-FMA one parent: 8 bf16 positions, scalar f32 accs
#define PFMA(vv, wv)                                              \
  { float wv_ = (wv);                                             \
    a0 += wv_ * __uint_as_float((unsigned)(vv)[0] << 16);         \
    a1 += wv_ * __uint_as_float((unsigned)(vv)[1] << 16);         \
    a2 += wv_ * __uint_as_float((unsigned)(vv)[2] << 16);         \
    a3 += wv_ * __uint_as_float((unsigned)(vv)[3] << 16);         \
    a4 += wv_ * __uint_as_float((unsigned)(vv)[4] << 16);         \
    a5 += wv_ * __uint_as_float((unsigned)(vv)[5] << 16);         \
    a6 += wv_ * __uint_as_float((unsigned)(vv)[6] << 16);         \
    a7 += wv_ * __uint_as_float((unsigned)(vv)[7] << 16); }

__global__ __launch_bounds__(NTHREADS, 1) void decoder_kernel(
    const float* __restrict__ prev, const int* __restrict__ pidx,
    const float* __restrict__ w, const float* __restrict__ b,
    const float* __restrict__ actf, float* __restrict__ out,
    float* __restrict__ outact) {
  extern __shared__ char xb[];               // [2048 rows][48 B] bf16 tile
  const int tid  = threadIdx.x;
  const int bid  = blockIdx.x;               // 0..255 (= tile)
  const int pos0 = bid * POS_TILE;

  // ---- stage prev[:, pos0:pos0+16] as bf16-RNE into 48B padded rows ----
  #pragma unroll
  for (int it = 0; it < 4; ++it) {
    int ci = (it << 10) + tid;               // 0..4095 (= r*2 + c)
    int r = ci >> 1, c = ci & 1;
    const float* sp = prev + r * NN + pos0 + (c << 3);
    f32x4 v0 = *(const f32x4*)sp;
    f32x4 v1 = *(const f32x4*)(sp + 4);
    u16x8 o;
    o[0] = f2bf_rne(v0.x); o[1] = f2bf_rne(v0.y);
    o[2] = f2bf_rne(v0.z); o[3] = f2bf_rne(v0.w);
    o[4] = f2bf_rne(v1.x); o[5] = f2bf_rne(v1.y);
    o[6] = f2bf_rne(v1.z); o[7] = f2bf_rne(v1.w);
    *(u16x8*)(xb + r * ROW_B + (c << 4)) = o;   // 16B-aligned (48 = 3*16)
  }
  __syncthreads();

  const int q  = tid & 1;                    // 16B chunk = 8 positions
  const int s  = tid >> 1;                   // node slot 0..511
  const int qb = q << 4;                     // byte offset within row

  for (int it = 0; it < 8; ++it) {
    int n = (it << 9) + s;
    const int4*   ip = (const int4*)(pidx + (n << 4));
    const float4* wp = (const float4*)(w + (n << 4));
    int4   i0 = ip[0], i1 = ip[1], i2 = ip[2], i3 = ip[3];
    float4 w0 = wp[0], w1 = wp[1], w2 = wp[2], w3 = wp[3];
    float  bk = b[n];
    float  g  = actf[n];                     // 0.0 / 1.0

    float a0 = bk, a1 = bk, a2 = bk, a3 = bk;
    float a4 = bk, a5 = bk, a6 = bk, a7 = bk;

    // batch 1: parents 0..7 — 8 independent ds_read_b128
    u16x8 v0 = *(const u16x8*)(xb + i0.x * ROW_B + qb);
    u16x8 v1 = *(const u16x8*)(xb + i0.y * ROW_B + qb);
    u16x8 v2 = *(const u16x8*)(xb + i0.z * ROW_B + qb);
    u16x8 v3 = *(const u16x8*)(xb + i0.w * ROW_B + qb);
    u16x8 v4 = *(const u16x8*)(xb + i1.x * ROW_B + qb);
    u16x8 v5 = *(const u16x8*)(xb + i1.y * ROW_B + qb);
    u16x8 v6 = *(const u16x8*)(xb + i1.z * ROW_B + qb);
    u16x8 v7 = *(const u16x8*)(xb + i1.w * ROW_B + qb);
    __builtin_amdgcn_sched_barrier(0);       // keep 8 reads in flight
    PFMA(v0, w0.x) PFMA(v1, w0.y) PFMA(v2, w0.z) PFMA(v3, w0.w)
    PFMA(v4, w1.x) PFMA(v5, w1.y) PFMA(v6, w1.z) PFMA(v7, w1.w)

    // batch 2: parents 8..15
    v0 = *(const u16x8*)(xb + i2.x * ROW_B + qb);
    v1 = *(const u16x8*)(xb + i2.y * ROW_B + qb);
    v2 = *(const u16x8*)(xb + i2.z * ROW_B + qb);
    v3 = *(const u16x8*)(xb + i2.w * ROW_B + qb);
    v4 = *(const u16x8*)(xb + i3.x * ROW_B + qb);
    v5 = *(const u16x8*)(xb + i3.y * ROW_B + qb);
    v6 = *(const u16x8*)(xb + i3.z * ROW_B + qb);
    v7 = *(const u16x8*)(xb + i3.w * ROW_B + qb);
    __builtin_amdgcn_sched_barrier(0);
    PFMA(v0, w2.x) PFMA(v1, w2.y) PFMA(v2, w2.z) PFMA(v3, w2.w)
    PFMA(v4, w3.x) PFMA(v5, w3.y) PFMA(v6, w3.z) PFMA(v7, w3.w)

    f32x4 o0, o1;
    o0.x = fast_tanh(a0) * g; o0.y = fast_tanh(a1) * g;
    o0.z = fast_tanh(a2) * g; o0.w = fast_tanh(a3) * g;
    o1.x = fast_tanh(a4) * g; o1.y = fast_tanh(a5) * g;
    o1.z = fast_tanh(a6) * g; o1.w = fast_tanh(a7) * g;

    // pair writes node n's full 64B line (lane covers 32B)
    float* op = out + ((size_t)n << 12) + pos0 + (q << 3);
    *(f32x4*)op       = o0;
    *(f32x4*)(op + 4) = o1;

    if (bid == 0 && q == 0) outact[n] = g;   // block 0, lanes q=0 cover all n
  }
}

extern "C" void kernel_launch(void* const* d_in, const int* in_sizes, int n_in,
                              void* d_out, int out_size, void* d_ws, size_t ws_size,
                              hipStream_t stream) {
  const float* prev  = (const float*)d_in[0];
  const void*  isact = d_in[1];
  const int*   pidx  = (const int*)d_in[2];
  const float* w     = (const float*)d_in[3];
  const float* b     = (const float*)d_in[4];
  float* out    = (float*)d_out;
  float* outact = out + OUT_ELEMS;

  (void)hipFuncSetAttribute((const void*)decoder_kernel,
                            hipFuncAttributeMaxDynamicSharedMemorySize, LDS_BYTES);

  act_kernel<<<K_NODES / 256, 256, 0, stream>>>(
      pidx, (const unsigned int*)isact, outact);
  decoder_kernel<<<NN / POS_TILE, NTHREADS, LDS_BYTES, stream>>>(
      prev, pidx, w, b, outact, out, outact);
}